// Round 4
// baseline (112.563 us; speedup 1.0000x reference)
//
#include <hip/hip_runtime.h>
#include <hip/hip_bf16.h>
#include <stdint.h>

#define DM 1024
#define NH 16
#define DH 64
#define BB 4
#define TT 1024
#define MR (BB*TT)

typedef __attribute__((ext_vector_type(8))) short bf16x8;
typedef __attribute__((ext_vector_type(4))) float f32x4;

typedef unsigned int __attribute__((address_space(1))) uint_g;
typedef unsigned int __attribute__((address_space(3))) uint_l;

static __device__ __forceinline__ void gload_lds16(const void* g, void* l) {
  __builtin_amdgcn_global_load_lds((const uint_g*)g, (uint_l*)l, 16, 0, 0);
}

static __device__ __forceinline__ void fence() { asm volatile("" ::: "memory"); }

static __device__ __forceinline__ unsigned short f2bf(float f) {
  union { float f; unsigned int u; } v; v.f = f;
  unsigned int r = v.u + 0x7fffu + ((v.u >> 16) & 1u);
  return (unsigned short)(r >> 16);
}
static __device__ __forceinline__ unsigned short f2bf_fast(float f) {
  union { float f; unsigned int u; } v; v.f = f;
  return (unsigned short)((v.u + 0x8000u) >> 16);   // P >= 0, finite: safe
}

__global__ __launch_bounds__(256) void k_cvt3(const float* __restrict__ x,
    const float* __restrict__ w1, const float* __restrict__ w2,
    unsigned short* __restrict__ xb, unsigned short* __restrict__ wqb,
    unsigned short* __restrict__ wob) {
  const int n1 = (MR * DM) / 4, n2 = (3 * DM * DM) / 4, n3 = (DM * DM) / 4;
  const int total = n1 + n2 + n3;
  for (int u = blockIdx.x * 256 + threadIdx.x; u < total; u += gridDim.x * 256) {
    const float* src; unsigned short* dst; int i;
    if (u < n1)           { src = x;  dst = xb;  i = u; }
    else if (u < n1 + n2) { src = w1; dst = wqb; i = u - n1; }
    else                  { src = w2; dst = wob; i = u - n1 - n2; }
    float4 v = reinterpret_cast<const float4*>(src)[i];
    ushort4 o;
    o.x = f2bf(v.x); o.y = f2bf(v.y); o.z = f2bf(v.z); o.w = f2bf(v.w);
    reinterpret_cast<ushort4*>(dst)[i] = o;
  }
}

// C = A @ B^T. 128x128 tile, BK=32, 4 waves. 3-buffer depth-2 pipeline with
// counted vmcnt (never 0 in steady state) + raw s_barrier (T3+T4).
// EPI=0: scatter q (x1/8), k [B,H,T,Dh], v^T [B,H,Dh,T].  EPI=1: fp32 C store.
template<int EPI>
__global__ __launch_bounds__(256) void k_gemm(
    const unsigned short* __restrict__ A, const unsigned short* __restrict__ Bw,
    float* __restrict__ Of, unsigned short* __restrict__ qb,
    unsigned short* __restrict__ kb, unsigned short* __restrict__ vtb,
    int N, int K, int tiles_n) {
  __shared__ unsigned short At[3][128 * 32];
  __shared__ unsigned short Bt[3][128 * 32];
  int tid = threadIdx.x;
  int w = tid >> 6, l = tid & 63;
  int l15 = l & 15, k8 = l >> 4;
  int nwg = gridDim.x;
  int cpx = nwg >> 3;                      // grid divisible by 8 (bijective XCD swizzle)
  int wg = blockIdx.x;
  int swz = (wg & 7) * cpx + (wg >> 3);
  int tm = swz / tiles_n, tn = swz % tiles_n;
  int m0 = tm << 7, n0 = tn << 7;

  f32x4 acc[4][4];
  #pragma unroll
  for (int i = 0; i < 4; ++i)
    #pragma unroll
    for (int j = 0; j < 4; ++j) acc[i][j] = (f32x4){0.f, 0.f, 0.f, 0.f};

  int srow = (w << 4) + (l >> 2);          // staging row, seg p=0
  int sch = l & 3;
  int mrb = ((w >> 1) << 6) + l15;
  int nrb = ((w & 1) << 6) + l15;

  auto stage = [&](int buf, int kk) {
    #pragma unroll
    for (int p = 0; p < 2; ++p) {
      int row = srow + (p << 6);
      int c = sch ^ ((row >> 1) & 3);      // pre-swizzled global source, linear LDS dest
      int seg = w + (p << 2);
      gload_lds16(A + (size_t)(m0 + row) * K + kk + (c << 3), &At[buf][seg << 9]);
      gload_lds16(Bw + (size_t)(n0 + row) * K + kk + (c << 3), &Bt[buf][seg << 9]);
    }
  };

  const int nt = K >> 5;
  stage(0, 0);
  stage(1, 32);
  asm volatile("s_waitcnt vmcnt(4)" ::: "memory");   // tile0 landed, tile1 flying
  fence(); __builtin_amdgcn_s_barrier(); fence();

  int rd = 0;
  for (int t = 0; t < nt; ++t) {
    int st = (rd == 0) ? 2 : rd - 1;       // (t+2) % 3
    if (t + 2 < nt) stage(st, (t + 2) << 5);
    bf16x8 a[4], b[4];
    #pragma unroll
    for (int mf = 0; mf < 4; ++mf) {
      int row = mrb + (mf << 4);
      a[mf] = *(const bf16x8*)&At[rd][(row << 5) + ((k8 ^ ((row >> 1) & 3)) << 3)];
    }
    #pragma unroll
    for (int nf = 0; nf < 4; ++nf) {
      int row = nrb + (nf << 4);
      b[nf] = *(const bf16x8*)&Bt[rd][(row << 5) + ((k8 ^ ((row >> 1) & 3)) << 3)];
    }
    #pragma unroll
    for (int mf = 0; mf < 4; ++mf)
      #pragma unroll
      for (int nf = 0; nf < 4; ++nf)
        acc[mf][nf] = __builtin_amdgcn_mfma_f32_16x16x32_bf16(a[mf], b[nf], acc[mf][nf], 0, 0, 0);
    if (t + 2 < nt)      { asm volatile("s_waitcnt vmcnt(4)" ::: "memory"); }
    else if (t + 1 < nt) { asm volatile("s_waitcnt vmcnt(0)" ::: "memory"); }
    fence(); __builtin_amdgcn_s_barrier(); fence();
    rd = (rd == 2) ? 0 : rd + 1;
  }

  #pragma unroll
  for (int mf = 0; mf < 4; ++mf) {
    #pragma unroll
    for (int nf = 0; nf < 4; ++nf) {
      int n = n0 + ((w & 1) << 6) + (nf << 4) + l15;
      int m_base = m0 + ((w >> 1) << 6) + (mf << 4) + (k8 << 2);
      if (EPI == 1) {
        #pragma unroll
        for (int r = 0; r < 4; ++r)
          Of[(size_t)(m_base + r) * N + n] = acc[mf][nf][r];
      } else {
        int s = n >> 10, rem = n & 1023;
        int h = rem >> 6, d = rem & 63;
        #pragma unroll
        for (int r = 0; r < 4; ++r) {
          int m = m_base + r;
          int bb = m >> 10, t = m & 1023;
          float v = acc[mf][nf][r];
          if (s == 0)
            qb[((size_t)(bb * NH + h) * TT + t) * DH + d] = f2bf(v * 0.125f);
          else if (s == 1)
            kb[((size_t)(bb * NH + h) * TT + t) * DH + d] = f2bf(v);
          else
            vtb[((size_t)(bb * NH + h) * DH + d) * TT + t] = f2bf(v);
        }
      }
    }
  }
}

// Flash attention: 8 waves, QBLK=128, KVBLK=64. 3-buffer counted-vmcnt
// pipeline, swapped QK^T, defer-max, setprio around MFMA clusters.
__global__ __launch_bounds__(512) void k_attn(
    const unsigned short* __restrict__ qb, const unsigned short* __restrict__ kb,
    const unsigned short* __restrict__ vtb, unsigned short* __restrict__ yb) {
  __shared__ unsigned short Kt[3][64 * 64];
  __shared__ unsigned short Vt[3][64 * 64];
  __shared__ unsigned short Pl[8][16][72];
  int tid = threadIdx.x, w = tid >> 6, l = tid & 63;
  int l15 = l & 15, k8 = l >> 4;
  int bh = blockIdx.x >> 3;
  int qt = blockIdx.x & 7;
  int q0 = qt << 7;
  const unsigned short* Kb = kb + (size_t)bh * TT * DH;
  const unsigned short* Vb = vtb + (size_t)bh * DH * TT;
  const unsigned short* Qb = qb + (size_t)bh * TT * DH;

  int qrow = q0 + (w << 4) + l15;
  bf16x8 qf[2];
  #pragma unroll
  for (int c = 0; c < 2; ++c)
    qf[c] = *(const bf16x8*)&Qb[(size_t)qrow * DH + (c << 5) + (k8 << 3)];

  f32x4 y[4];
  #pragma unroll
  for (int i = 0; i < 4; ++i) y[i] = (f32x4){0.f, 0.f, 0.f, 0.f};
  float mrow = -INFINITY, lrow = 0.f;

  int srow = l >> 3;
  int sch = l & 7;

  auto stage = [&](int buf, int j0) {
    int row = (w << 3) + srow;              // 8 rows per wave
    int c = sch ^ (row & 7);
    gload_lds16(Kb + (size_t)(j0 + row) * DH + (c << 3), &Kt[buf][(w << 3) << 6]);
    gload_lds16(Vb + (size_t)row * TT + j0 + (c << 3), &Vt[buf][(w << 3) << 6]);
  };

  const int ns = (q0 >> 6) + 2;             // kv tiles: 2*qt + 2
  stage(0, 0);
  stage(1, 64);
  asm volatile("s_waitcnt vmcnt(2)" ::: "memory");
  fence(); __builtin_amdgcn_s_barrier(); fence();

  int rd = 0;
  for (int t = 0; t < ns; ++t) {
    int j0 = t << 6;
    int st = (rd == 0) ? 2 : rd - 1;
    if (t + 2 < ns) stage(st, (t + 2) << 6);

    f32x4 s[4];
    #pragma unroll
    for (int f = 0; f < 4; ++f) s[f] = (f32x4){0.f, 0.f, 0.f, 0.f};
    __builtin_amdgcn_s_setprio(1);
    #pragma unroll
    for (int c = 0; c < 2; ++c) {
      #pragma unroll
      for (int f = 0; f < 4; ++f) {
        int row = (f << 4) + l15;
        bf16x8 ak = *(const bf16x8*)&Kt[rd][(row << 6) + ((((c << 2) + k8) ^ (row & 7)) << 3)];
        s[f] = __builtin_amdgcn_mfma_f32_16x16x32_bf16(ak, qf[c], s[f], 0, 0, 0);
      }
    }
    __builtin_amdgcn_s_setprio(0);

    if (j0 + 64 > q0 + (w << 4)) {          // diagonal band for this wave (uniform branch)
      #pragma unroll
      for (int f = 0; f < 4; ++f)
        #pragma unroll
        for (int r = 0; r < 4; ++r)
          if (j0 + (f << 4) + (k8 << 2) + r > qrow) s[f][r] = -INFINITY;
    }

    float pmax = -INFINITY;
    #pragma unroll
    for (int f = 0; f < 4; ++f)
      #pragma unroll
      for (int r = 0; r < 4; ++r) pmax = fmaxf(pmax, s[f][r]);
    pmax = fmaxf(pmax, __shfl_xor(pmax, 16, 64));
    pmax = fmaxf(pmax, __shfl_xor(pmax, 32, 64));

    bool skip = __all(pmax - mrow <= 8.0f);          // T13 defer-max
    float mnew = skip ? mrow : fmaxf(mrow, pmax);
    float psum = 0.f;
    #pragma unroll
    for (int f = 0; f < 4; ++f)
      #pragma unroll
      for (int r = 0; r < 4; ++r) {
        float p = __expf(s[f][r] - mnew);
        s[f][r] = p;
        psum += p;
      }
    psum += __shfl_xor(psum, 16, 64);
    psum += __shfl_xor(psum, 32, 64);
    if (!skip) {
      float alpha = __expf(mrow - mnew);
      lrow *= alpha;
      #pragma unroll
      for (int mf = 0; mf < 4; ++mf) y[mf] *= alpha;
      mrow = mnew;
    }
    lrow += psum;

    #pragma unroll
    for (int f = 0; f < 4; ++f) {
      ushort4 pk;
      pk.x = f2bf_fast(s[f][0]); pk.y = f2bf_fast(s[f][1]);
      pk.z = f2bf_fast(s[f][2]); pk.w = f2bf_fast(s[f][3]);
      *(ushort4*)&Pl[w][l15][(f << 4) + (k8 << 2)] = pk;
    }
    asm volatile("s_waitcnt lgkmcnt(0)" ::: "memory");
    __builtin_amdgcn_sched_barrier(0);

    __builtin_amdgcn_s_setprio(1);
    #pragma unroll
    for (int c = 0; c < 2; ++c) {
      bf16x8 bp = *(const bf16x8*)&Pl[w][l15][(c << 5) + (k8 << 3)];
      #pragma unroll
      for (int mf = 0; mf < 4; ++mf) {
        int dr = (mf << 4) + l15;
        bf16x8 av = *(const bf16x8*)&Vt[rd][(dr << 6) + ((((c << 2) + k8) ^ (dr & 7)) << 3)];
        y[mf] = __builtin_amdgcn_mfma_f32_16x16x32_bf16(av, bp, y[mf], 0, 0, 0);
      }
    }
    __builtin_amdgcn_s_setprio(0);

    if (t + 2 < ns)      { asm volatile("s_waitcnt vmcnt(2)" ::: "memory"); }
    else if (t + 1 < ns) { asm volatile("s_waitcnt vmcnt(0)" ::: "memory"); }
    fence(); __builtin_amdgcn_s_barrier(); fence();
    rd = (rd == 2) ? 0 : rd + 1;
  }

  float inv = 1.f / lrow;
  int bb = bh >> 4, h = bh & 15;
  #pragma unroll
  for (int mf = 0; mf < 4; ++mf) {
    ushort4 o;
    o.x = f2bf(y[mf][0] * inv);
    o.y = f2bf(y[mf][1] * inv);
    o.z = f2bf(y[mf][2] * inv);
    o.w = f2bf(y[mf][3] * inv);
    *(ushort4*)&yb[((size_t)(bb * TT + qrow) << 10) + (h << 6) + (mf << 4) + (k8 << 2)] = o;
  }
}

extern "C" void kernel_launch(void* const* d_in, const int* in_sizes, int n_in,
                              void* d_out, int out_size, void* d_ws, size_t ws_size,
                              hipStream_t stream) {
  const float* x    = (const float*)d_in[0];
  const float* wqkv = (const float*)d_in[1];
  const float* wout = (const float*)d_in[2];
  char* ws = (char*)d_ws;
  unsigned short* xb  = (unsigned short*)(ws + (size_t)0);
  unsigned short* wqb = (unsigned short*)(ws + ((size_t)8  << 20));
  unsigned short* wob = (unsigned short*)(ws + ((size_t)14 << 20));
  unsigned short* qbv = (unsigned short*)(ws + ((size_t)16 << 20));
  unsigned short* kbv = (unsigned short*)(ws + ((size_t)24 << 20));
  unsigned short* vtb = (unsigned short*)(ws + ((size_t)32 << 20));
  unsigned short* yb  = (unsigned short*)(ws + ((size_t)40 << 20));

  k_cvt3<<<2048, 256, 0, stream>>>(x, wqkv, wout, xb, wqb, wob);
  k_gemm<0><<<768, 256, 0, stream>>>(xb, wqb, nullptr, qbv, kbv, vtb, 3 * DM, DM, 24);
  k_attn<<<512, 512, 0, stream>>>(qbv, kbv, vtb, yb);
  k_gemm<1><<<256, 256, 0, stream>>>(yb, wob, (float*)d_out, nullptr, nullptr, nullptr, DM, DM, 8);
}